// Round 1
// baseline (227.629 us; speedup 1.0000x reference)
//
#include <hip/hip_runtime.h>

// out[i] = [x2, x3, -(k1*x0 + k2*(x0-x1)), k2*(x0-x1)] per row of x (B,4).
// Pure streaming: one float4 load + one float4 store per row.
__global__ __launch_bounds__(256) void lagrangian_ode_kernel(
    const float4* __restrict__ x,
    const float* __restrict__ k1p,
    const float* __restrict__ k2p,
    float4* __restrict__ out,
    int n_rows) {
    int i = blockIdx.x * blockDim.x + threadIdx.x;
    if (i >= n_rows) return;
    const float k1 = k1p[0];
    const float k2 = k2p[0];
    float4 v = x[i];
    float d = v.x - v.y;          // q0 - q1
    float4 o;
    o.x = v.z;                    // qd0
    o.y = v.w;                    // qd1
    o.z = -(k1 * v.x + k2 * d);   // qdd0
    o.w = k2 * d;                 // qdd1
    out[i] = o;
}

extern "C" void kernel_launch(void* const* d_in, const int* in_sizes, int n_in,
                              void* d_out, int out_size, void* d_ws, size_t ws_size,
                              hipStream_t stream) {
    // setup_inputs order: t (1), x (B*4), k1 (1), k2 (1)
    const float4* x  = (const float4*)d_in[1];
    const float*  k1 = (const float*)d_in[2];
    const float*  k2 = (const float*)d_in[3];
    float4* out = (float4*)d_out;

    int n_rows = in_sizes[1] / 4;   // B = 8388608
    int block = 256;
    int grid = (n_rows + block - 1) / block;
    lagrangian_ode_kernel<<<grid, block, 0, stream>>>(x, k1, k2, out, n_rows);
}

// Round 2
// 226.354 us; speedup vs baseline: 1.0056x; 1.0056x over previous
//
#include <hip/hip_runtime.h>

// out[i] = [x2, x3, -(k1*x0 + k2*(x0-x1)), k2*(x0-x1)] per row of x (B,4).
// Pure streaming, touch-once data: nontemporal float4 load/store.
// Minimal traffic: 128 MiB read + 128 MiB write; no reuse exists.

typedef float f32x4 __attribute__((ext_vector_type(4)));

__global__ __launch_bounds__(256) void lagrangian_ode_kernel(
    const f32x4* __restrict__ x,
    const float* __restrict__ k1p,
    const float* __restrict__ k2p,
    f32x4* __restrict__ out,
    int n_rows) {
    int i = blockIdx.x * blockDim.x + threadIdx.x;
    if (i >= n_rows) return;
    const float k1 = k1p[0];
    const float k2 = k2p[0];
    f32x4 v = __builtin_nontemporal_load(&x[i]);
    float d = v.x - v.y;          // q0 - q1
    f32x4 o;
    o.x = v.z;                    // qd0
    o.y = v.w;                    // qd1
    o.z = -(k1 * v.x + k2 * d);   // qdd0 = -(dV/dq0)
    o.w = k2 * d;                 // qdd1 = -(dV/dq1)
    __builtin_nontemporal_store(o, &out[i]);
}

extern "C" void kernel_launch(void* const* d_in, const int* in_sizes, int n_in,
                              void* d_out, int out_size, void* d_ws, size_t ws_size,
                              hipStream_t stream) {
    // setup_inputs order: t (1), x (B*4), k1 (1), k2 (1)
    const f32x4* x  = (const f32x4*)d_in[1];
    const float* k1 = (const float*)d_in[2];
    const float* k2 = (const float*)d_in[3];
    f32x4* out = (f32x4*)d_out;

    int n_rows = in_sizes[1] / 4;   // B = 8388608
    int block = 256;
    int grid = (n_rows + block - 1) / block;
    lagrangian_ode_kernel<<<grid, block, 0, stream>>>(x, k1, k2, out, n_rows);
}